// Round 1
// 480.909 us; speedup vs baseline: 1.0132x; 1.0132x over previous
//
#include <hip/hip_runtime.h>
#include <hip/hip_bf16.h>

typedef __attribute__((ext_vector_type(8))) short short8;
typedef __attribute__((ext_vector_type(8))) unsigned short ushort8;
typedef __attribute__((ext_vector_type(4))) float f32x4;

static constexpr int NN = 50000;   // nodes
static constexpr int NE = 800000;  // edges
static constexpr int SCAN_B = 196; // ceil(NN/256)
static constexpr int NBLK = (NN + 63) / 64;  // 782 blocks of 64 rows

#define MFMA16x16x32 __builtin_amdgcn_mfma_f32_16x16x32_bf16

__device__ __forceinline__ float b2f(unsigned short u){
  unsigned v = ((unsigned)u) << 16;
  return __builtin_bit_cast(float, v);
}
__device__ __forceinline__ unsigned short f2b(float f){
  unsigned x = __builtin_bit_cast(unsigned, f);
  unsigned r = (x + 0x7fffu + ((x >> 16) & 1u)) >> 16;  // RNE
  return (unsigned short)r;
}
__device__ __forceinline__ short8 u2s(ushort8 v){
  return __builtin_bit_cast(short8, v);
}

// ---------------- static device scratch
__device__ __align__(256) int   g_isf32;
__device__ __align__(256) unsigned short g_W1t  [112 * 512];
__device__ __align__(256) unsigned short g_W2t  [112 * 128];
__device__ __align__(256) unsigned short g_WselfT[112 * 128];
__device__ __align__(256) unsigned short g_WrelT [112 * 128];
__device__ __align__(256) unsigned short g_c1Wt [112 * 128];
__device__ __align__(256) unsigned short g_c2Wt [64 * 128];
__device__ __align__(256) unsigned short g_bufA[(size_t)NN * 128];  // holds [N,64] c2 out
__device__ __align__(256) unsigned short g_bufB[(size_t)NN * 128];  // x2
__device__ __align__(256) unsigned short g_bufC[(size_t)NN * 128];  // x3
__device__ __align__(256) int   g_deg[NN];
__device__ __align__(256) int   g_rowptr[NN + 1];
__device__ __align__(256) int   g_cursor[NN];
__device__ __align__(256) int   g_colidx[NE];
__device__ __align__(256) float g_dinv[NN];
__device__ __align__(256) int   g_partial[256];

__device__ __forceinline__ float ld_in(const void* p, int idx, int isf32){
  if (isf32) return ((const float*)p)[idx];
  return b2f(((const unsigned short*)p)[idx]);
}

// ---------------- prep kernels ----------------
__global__ void k_detect_zero(const unsigned short* __restrict__ x){
  if (blockIdx.x == 0){
    __shared__ int sh[256];
    int tid = threadIdx.x;
    int cnt = 0;
    for (int j = 0; j < 16; j++){
      unsigned short h = x[(size_t)(tid * 16 + j) * 2];
      int e = (h >> 7) & 0xFF;
      if (e >= 90 && e <= 160) cnt++;
    }
    sh[tid] = cnt;
    __syncthreads();
    for (int off = 128; off > 0; off >>= 1){
      if (tid < off) sh[tid] += sh[tid + off];
      __syncthreads();
    }
    if (tid == 0) g_isf32 = (sh[0] < 2458) ? 1 : 0;
  } else {
    int i = (blockIdx.x - 1) * 256 + threadIdx.x;
    if (i < NN){ g_deg[i] = 0; g_cursor[i] = 0; }
  }
}

__device__ __forceinline__ void xp_one(const void* W, unsigned short* Wt, int idx,
                                       int K, int Nc, int Kpad, int isf32){
  int n = idx / Kpad;
  int k = idx - n * Kpad;
  float v = 0.f;
  if (n < Nc && k < K) v = ld_in(W, k * Nc + n, isf32);
  Wt[idx] = f2b(v);
}
__global__ void k_transpose_all(const void* W1, const void* W2, const void* Wself,
                                const void* Wrel, const void* c1W, const void* c2W){
  int idx = blockIdx.x * 256 + threadIdx.x;
  const int isf32 = g_isf32;
  if (idx < 57344){ xp_one(W1, g_W1t, idx, 500, 100, 512, isf32); return; }
  idx -= 57344;
  if (idx < 14336){ xp_one(W2,    g_W2t,    idx, 100, 100, 128, isf32); return; }
  idx -= 14336;
  if (idx < 14336){ xp_one(Wself, g_WselfT, idx, 100, 100, 128, isf32); return; }
  idx -= 14336;
  if (idx < 14336){ xp_one(Wrel,  g_WrelT,  idx, 100, 100, 128, isf32); return; }
  idx -= 14336;
  if (idx < 14336){ xp_one(c1W,   g_c1Wt,   idx, 100, 100, 128, isf32); return; }
  idx -= 14336;
  if (idx < 8192){  xp_one(c2W,   g_c2Wt,   idx, 100, 64,  128, isf32); }
}

__global__ void k_deg(const int* __restrict__ tgt){
  int e = blockIdx.x * 256 + threadIdx.x;
  if (e < NE) atomicAdd(&g_deg[tgt[e]], 1);
}
__global__ __launch_bounds__(256) void k_scan1(){
  __shared__ int sh[256];
  int t = threadIdx.x;
  int i = blockIdx.x * 256 + t;
  int val = (i < NN) ? g_deg[i] : 0;
  sh[t] = val; __syncthreads();
#pragma unroll
  for (int off = 1; off < 256; off <<= 1){
    int v = (t >= off) ? sh[t - off] : 0;
    __syncthreads(); sh[t] += v; __syncthreads();
  }
  if (i < NN){ g_rowptr[i] = sh[t] - val; g_dinv[i] = rsqrtf((float)(val + 1)); }
  if (t == 255) g_partial[blockIdx.x] = sh[255];
}
__global__ __launch_bounds__(256) void k_scan2(){
  __shared__ int sh[256];
  int t = threadIdx.x;
  int val = (t < SCAN_B) ? g_partial[t] : 0;
  sh[t] = val; __syncthreads();
#pragma unroll
  for (int off = 1; off < 256; off <<= 1){
    int v = (t >= off) ? sh[t - off] : 0;
    __syncthreads(); sh[t] += v; __syncthreads();
  }
  if (t < SCAN_B) g_partial[t] = sh[t] - val;
  if (t == 255) g_rowptr[NN] = sh[255];
}
__global__ __launch_bounds__(256) void k_scan3(){
  int i = blockIdx.x * 256 + threadIdx.x;
  if (i < NN) g_rowptr[i] += g_partial[blockIdx.x];
}
__global__ void k_fill(const int* __restrict__ src, const int* __restrict__ tgt){
  int e = blockIdx.x * 256 + threadIdx.x;
  if (e >= NE) return;
  int t = tgt[e];
  int pos = g_rowptr[t] + atomicAdd(&g_cursor[t], 1);
  g_colidx[pos] = src[e];
}

// ---------------- shared device helpers ----------------

// Per-wave epilogue over acc[7] (rows q*4+r of a 16-row tile, cols t*16+m).
// DO_LN: bias+LN+ReLU; else bias+ReLU. Writes bf16 rows of stride rstride,
// zero-padding cols 100..127. Rows are stored iff (grow0 + local_row) < NN.
template<int DO_LN>
__device__ __forceinline__ void wave_epi(const f32x4* acc, unsigned short* dst,
    int rstride, int grow0, int lane, int isf32,
    const void* bias, const void* gm, const void* be){
  const int m = lane & 15;
  const int q = lane >> 4;
  float bf_[7], gf_[7], ef_[7];
#pragma unroll
  for (int t = 0; t < 7; t++){
    int col = t * 16 + m;
    bool ok = col < 100;
    bf_[t] = ok ? ld_in(bias, col, isf32) : 0.f;
    if (DO_LN){
      gf_[t] = ok ? ld_in(gm, col, isf32) : 0.f;
      ef_[t] = ok ? ld_in(be, col, isf32) : 0.f;
    }
  }
#pragma unroll
  for (int r = 0; r < 4; r++){
    int rl = q * 4 + r;
    float vals[7], s1 = 0.f, s2 = 0.f;
#pragma unroll
    for (int t = 0; t < 7; t++){
      int col = t * 16 + m;
      float v = (col < 100) ? (acc[t][r] + bf_[t]) : 0.f;
      vals[t] = v; s1 += v; s2 += v * v;
    }
    if (DO_LN){
#pragma unroll
      for (int msk = 1; msk < 16; msk <<= 1){
        s1 += __shfl_xor(s1, msk, 64);
        s2 += __shfl_xor(s2, msk, 64);
      }
      float mu = s1 * 0.01f;
      float var = fmaxf(s2 * 0.01f - mu * mu, 0.f);
      float rstd = rsqrtf(var + 1e-5f);
#pragma unroll
      for (int t = 0; t < 7; t++)
        vals[t] = (vals[t] - mu) * rstd * gf_[t] + ef_[t];
    }
    if (grow0 + rl < NN){
      unsigned short* orow = dst + (size_t)rl * rstride;
#pragma unroll
      for (int t = 0; t < 7; t++){
        int col = t * 16 + m;
        float y = fmaxf(vals[t], 0.f);
        orow[col] = f2b((col < 100) ? y : 0.f);
      }
      orow[112 + m] = 0;
    }
  }
}

// gather-aggregate 64 nodes x 128 cols into bf16 LDS tile (stride 136).
// 4 threads/node, 32 cols each. MODE 0: plain sum; MODE 1: sym-norm + self.
// Pads (cols 100..127) come out zero because source rows are zero-padded.
template<int MODE>
__device__ __forceinline__ void agg_tile(const unsigned short* __restrict__ x,
    unsigned short* aggT, int tid, int brow0){
  const int nl = tid >> 2;          // 0..63
  const int c0 = (tid & 3) * 32;    // 0,32,64,96
  const int node = min(brow0 + nl, NN - 1);
  const float wt = (MODE != 0) ? g_dinv[node] : 1.f;
  float a[32];
#pragma unroll
  for (int k = 0; k < 32; k++) a[k] = 0.f;
  const int p0 = g_rowptr[node], p1 = g_rowptr[node + 1];
  for (int p = p0; p < p1; p += 2){
    int s0 = g_colidx[p];
    bool ok1 = (p + 1) < p1;
    int s1 = ok1 ? g_colidx[p + 1] : node;
    float w0 = (MODE != 0) ? g_dinv[s0] * wt : 1.f;
    float w1 = ok1 ? ((MODE != 0) ? g_dinv[s1] * wt : 1.f) : 0.f;
    ushort8 r0[4], r1[4];
#pragma unroll
    for (int u = 0; u < 4; u++){
      r0[u] = *reinterpret_cast<const ushort8*>(&x[(size_t)s0 * 128 + c0 + u * 8]);
      r1[u] = *reinterpret_cast<const ushort8*>(&x[(size_t)s1 * 128 + c0 + u * 8]);
    }
#pragma unroll
    for (int u = 0; u < 4; u++)
#pragma unroll
      for (int k = 0; k < 8; k++){
        a[u * 8 + k] += w0 * b2f((unsigned short)r0[u][k]);
        a[u * 8 + k] += w1 * b2f((unsigned short)r1[u][k]);
      }
  }
  if (MODE != 0){
    float ws = wt * wt;
#pragma unroll
    for (int u = 0; u < 4; u++){
      ushort8 sv = *reinterpret_cast<const ushort8*>(&x[(size_t)node * 128 + c0 + u * 8]);
#pragma unroll
      for (int k = 0; k < 8; k++) a[u * 8 + k] += ws * b2f((unsigned short)sv[k]);
    }
  }
  unsigned short* arow = aggT + nl * 136 + c0;
#pragma unroll
  for (int u = 0; u < 4; u++){
    ushort8 o;
#pragma unroll
    for (int k = 0; k < 8; k++) o[k] = f2b(a[u * 8 + k]);
    *reinterpret_cast<ushort8*>(&arow[u * 8]) = o;
  }
}

// ---------------- fused kernels ----------------
// 64 rows/block, 4 waves, each wave owns a full-K 16-row tile: no K-split,
// no cross-wave reduction LDS, per-wave epilogues.

__global__ __launch_bounds__(256, 4) void k_gemm12(const void* __restrict__ Aext,
    const void* b1, const void* gm1, const void* be1,
    const void* b2, const void* gm2, const void* be2){
  __shared__ unsigned short xT[4][16][136];
  const int tid = threadIdx.x;
  const int w = tid >> 6, lane = tid & 63;
  const int m = lane & 15, q = lane >> 4;
  const int row0 = blockIdx.x * 64 + w * 16;
  const int isf32 = g_isf32;
  const int arow = min(row0 + m, NN - 1);

  // GEMM1: full K=500 (padded 512) per wave
  f32x4 acc[7] = {};
  if (isf32){
    const float* base = (const float*)Aext + (size_t)arow * 500;
#pragma unroll 4
    for (int kc = 0; kc < 16; kc++){
      int col = kc * 32 + q * 8;
      f32x4 lo = *reinterpret_cast<const f32x4*>(base + min(col, 496));
      f32x4 hi = *reinterpret_cast<const f32x4*>(base + min(col + 4, 496));
      short8 a = {(short)f2b(lo[0]), (short)f2b(lo[1]), (short)f2b(lo[2]), (short)f2b(lo[3]),
                  (short)f2b(hi[0]), (short)f2b(hi[1]), (short)f2b(hi[2]), (short)f2b(hi[3])};
#pragma unroll
      for (int t = 0; t < 7; t++){
        short8 b = *reinterpret_cast<const short8*>(g_W1t + (size_t)(t * 16 + m) * 512 + col);
        acc[t] = MFMA16x16x32(a, b, acc[t], 0, 0, 0);
      }
    }
  } else {
    const unsigned short* base = (const unsigned short*)Aext + (size_t)arow * 500;
#pragma unroll 4
    for (int kc = 0; kc < 16; kc++){
      int col = kc * 32 + q * 8;
      ushort4 lo = *reinterpret_cast<const ushort4*>(base + min(col, 496));
      ushort4 hi = *reinterpret_cast<const ushort4*>(base + min(col + 4, 496));
      short8 a = {(short)lo.x, (short)lo.y, (short)lo.z, (short)lo.w,
                  (short)hi.x, (short)hi.y, (short)hi.z, (short)hi.w};
#pragma unroll
      for (int t = 0; t < 7; t++){
        short8 b = *reinterpret_cast<const short8*>(g_W1t + (size_t)(t * 16 + m) * 512 + col);
        acc[t] = MFMA16x16x32(a, b, acc[t], 0, 0, 0);
      }
    }
  }
  // LN1 + ReLU -> per-wave bf16 LDS tile
  wave_epi<1>(acc, &xT[w][0][0], 136, 0, lane, isf32, b1, gm1, be1);
  __syncthreads();

  // GEMM2: K=100 (padded 128) per wave
  f32x4 acc2[7] = {};
#pragma unroll
  for (int kc = 0; kc < 4; kc++){
    int k0 = kc * 32 + q * 8;
    short8 a = u2s(*reinterpret_cast<const ushort8*>(&xT[w][m][k0]));
#pragma unroll
    for (int t = 0; t < 7; t++){
      short8 b = *reinterpret_cast<const short8*>(g_W2t + (size_t)(t * 16 + m) * 128 + k0);
      acc2[t] = MFMA16x16x32(a, b, acc2[t], 0, 0, 0);
    }
  }
  wave_epi<1>(acc2, g_bufB + (size_t)row0 * 128, 128, row0, lane, isf32, b2, gm2, be2);
}

// RGCN: agg(bufB)->LDS, dual GEMM (bufB@Wself + agg@Wrel), bias+ReLU -> bufC.
__global__ __launch_bounds__(256, 4) void k_rgcn_f(const void* rb){
  __shared__ unsigned short aggT[64 * 136];
  const int tid = threadIdx.x;
  const int brow0 = blockIdx.x * 64;
  agg_tile<0>(g_bufB, aggT, tid, brow0);
  __syncthreads();

  const int w = tid >> 6, lane = tid & 63;
  const int m = lane & 15, q = lane >> 4;
  const int row0 = brow0 + w * 16;
  const int arow = min(row0 + m, NN - 1);
  const int isf32 = g_isf32;
  f32x4 acc[7] = {};
#pragma unroll
  for (int kc = 0; kc < 4; kc++){
    int k0 = kc * 32 + q * 8;
    short8 a1 = u2s(*reinterpret_cast<const ushort8*>(&g_bufB[(size_t)arow * 128 + k0]));
#pragma unroll
    for (int t = 0; t < 7; t++){
      short8 b = *reinterpret_cast<const short8*>(g_WselfT + (size_t)(t * 16 + m) * 128 + k0);
      acc[t] = MFMA16x16x32(a1, b, acc[t], 0, 0, 0);
    }
    short8 a2 = u2s(*reinterpret_cast<const ushort8*>(&aggT[(w * 16 + m) * 136 + k0]));
#pragma unroll
    for (int t = 0; t < 7; t++){
      short8 b = *reinterpret_cast<const short8*>(g_WrelT + (size_t)(t * 16 + m) * 128 + k0);
      acc[t] = MFMA16x16x32(a2, b, acc[t], 0, 0, 0);
    }
  }
  wave_epi<0>(acc, g_bufC + (size_t)row0 * 128, 128, row0, lane, isf32, rb, nullptr, nullptr);
}

// conv1+conv2: aggnorm(bufC)->LDS, c1 GEMM+bias+ReLU->LDS (tile reuse),
// c2 GEMM -> bufA[N,64].
__global__ __launch_bounds__(256, 4) void k_conv_f(const void* c1b){
  __shared__ unsigned short aggT[64 * 136];
  const int tid = threadIdx.x;
  const int brow0 = blockIdx.x * 64;
  agg_tile<1>(g_bufC, aggT, tid, brow0);
  __syncthreads();

  const int w = tid >> 6, lane = tid & 63;
  const int m = lane & 15, q = lane >> 4;
  const int row0 = brow0 + w * 16;
  const int isf32 = g_isf32;
  unsigned short* tile = aggT + w * 16 * 136;

  f32x4 acc[7] = {};
#pragma unroll
  for (int kc = 0; kc < 4; kc++){
    int k0 = kc * 32 + q * 8;
    short8 a = u2s(*reinterpret_cast<const ushort8*>(&tile[m * 136 + k0]));
#pragma unroll
    for (int t = 0; t < 7; t++){
      short8 b = *reinterpret_cast<const short8*>(g_c1Wt + (size_t)(t * 16 + m) * 128 + k0);
      acc[t] = MFMA16x16x32(a, b, acc[t], 0, 0, 0);
    }
  }
  __syncthreads();  // all agg reads complete before tile overwrite
  wave_epi<0>(acc, tile, 136, 0, lane, isf32, c1b, nullptr, nullptr);  // tile reused as x4
  __syncthreads();

  // c2: [16,100] @ c2Wt -> [16,64] (bias + log_softmax applied downstream)
  f32x4 acc2[4] = {};
#pragma unroll
  for (int kc = 0; kc < 4; kc++){
    int k0 = kc * 32 + q * 8;
    short8 a = u2s(*reinterpret_cast<const ushort8*>(&tile[m * 136 + k0]));
#pragma unroll
    for (int t = 0; t < 4; t++){
      short8 b = *reinterpret_cast<const short8*>(g_c2Wt + (size_t)(t * 16 + m) * 128 + k0);
      acc2[t] = MFMA16x16x32(a, b, acc2[t], 0, 0, 0);
    }
  }
#pragma unroll
  for (int r = 0; r < 4; r++){
    int row = row0 + q * 4 + r;
    if (row < NN){
      unsigned short* orow = g_bufA + (size_t)row * 64;
#pragma unroll
      for (int t = 0; t < 4; t++) orow[t * 16 + m] = f2b(acc2[t][r]);
    }
  }
}

// conv2 aggregate (64-col rows in bufA) + bias + log_softmax -> out
__global__ __launch_bounds__(256) void k_agg_lsm(const void* __restrict__ bias,
                                                 void* __restrict__ outv){
  const int isf32 = g_isf32;
  int node = blockIdx.x * 32 + (threadIdx.x >> 3);
  if (node >= NN) return;
  const int c8 = (threadIdx.x & 7) * 8;
  float wt = g_dinv[node];
  float a[4][8];
#pragma unroll
  for (int j = 0; j < 4; j++)
#pragma unroll
    for (int k = 0; k < 8; k++) a[j][k] = 0.f;
  int p0 = g_rowptr[node], p1 = g_rowptr[node + 1];
  for (int p = p0; p < p1; p += 4){
    int sj[4]; float wj[4];
#pragma unroll
    for (int j = 0; j < 4; j++){
      bool ok = (p + j) < p1;
      sj[j] = ok ? g_colidx[p + j] : node;
      wj[j] = ok ? g_dinv[sj[j]] * wt : 0.f;
    }
    ushort8 r[4];
#pragma unroll
    for (int j = 0; j < 4; j++)
      r[j] = *reinterpret_cast<const ushort8*>(&g_bufA[(size_t)sj[j] * 64 + c8]);
#pragma unroll
    for (int j = 0; j < 4; j++)
#pragma unroll
      for (int k = 0; k < 8; k++) a[j][k] += wj[j] * b2f((unsigned short)r[j][k]);
  }
  float ws = wt * wt;
  ushort8 sv = *reinterpret_cast<const ushort8*>(&g_bufA[(size_t)node * 64 + c8]);
#pragma unroll
  for (int k = 0; k < 8; k++) a[0][k] += ws * b2f((unsigned short)sv[k]);

  float v[8], mx = -1e30f;
#pragma unroll
  for (int k = 0; k < 8; k++){
    v[k] = a[0][k] + a[1][k] + a[2][k] + a[3][k] + ld_in(bias, c8 + k, isf32);
    mx = fmaxf(mx, v[k]);
  }
#pragma unroll
  for (int msk = 1; msk < 8; msk <<= 1) mx = fmaxf(mx, __shfl_xor(mx, msk, 64));
  float se = 0.f;
#pragma unroll
  for (int k = 0; k < 8; k++) se += expf(v[k] - mx);
#pragma unroll
  for (int msk = 1; msk < 8; msk <<= 1) se += __shfl_xor(se, msk, 64);
  float lse = logf(se);
  size_t ro = (size_t)node * 64 + c8;
  if (isf32){
    float* o = (float*)outv + ro;
#pragma unroll
    for (int k = 0; k < 8; k++) o[k] = v[k] - mx - lse;
  } else {
    unsigned short* o = (unsigned short*)outv + ro;
#pragma unroll
    for (int k = 0; k < 8; k++) o[k] = f2b(v[k] - mx - lse);
  }
}

extern "C" void kernel_launch(void* const* d_in, const int* in_sizes, int n_in,
                              void* d_out, int out_size, void* d_ws, size_t ws_size,
                              hipStream_t stream){
  (void)in_sizes; (void)n_in; (void)out_size; (void)d_ws; (void)ws_size;
  const void* data_x = d_in[0];
  const int* ei = (const int*)d_in[1];
  const int* src = ei;
  const int* tgt = ei + NE;
  const void *W1 = d_in[3], *b1 = d_in[4], *gm1 = d_in[5], *be1 = d_in[6];
  const void *W2 = d_in[7], *b2 = d_in[8], *gm2 = d_in[9], *be2 = d_in[10];
  const void *Wrel = d_in[11], *Wself = d_in[12], *rb = d_in[13];
  const void *c1W = d_in[14], *c1b = d_in[15];
  const void *c2W = d_in[16], *c2b = d_in[17];

  k_detect_zero<<<1 + (NN + 255) / 256, 256, 0, stream>>>((const unsigned short*)data_x);
  k_transpose_all<<<(122880 + 255) / 256, 256, 0, stream>>>(W1, W2, Wself, Wrel, c1W, c2W);

  k_deg<<<(NE + 255) / 256, 256, 0, stream>>>(tgt);
  k_scan1<<<SCAN_B, 256, 0, stream>>>();
  k_scan2<<<1, 256, 0, stream>>>();
  k_scan3<<<SCAN_B, 256, 0, stream>>>();
  k_fill<<<(NE + 255) / 256, 256, 0, stream>>>(src, tgt);

  k_gemm12<<<NBLK, 256, 0, stream>>>(data_x, b1, gm1, be1, b2, gm2, be2); // -> bufB
  k_rgcn_f<<<NBLK, 256, 0, stream>>>(rb);                                 // bufB -> bufC
  k_conv_f<<<NBLK, 256, 0, stream>>>(c1b);                                // bufC -> bufA[N,64]
  k_agg_lsm<<<(NN + 31) / 32, 256, 0, stream>>>(c2b, d_out);              // bufA -> out
}

// Round 2
// 478.318 us; speedup vs baseline: 1.0187x; 1.0054x over previous
//
#include <hip/hip_runtime.h>
#include <hip/hip_bf16.h>

typedef __attribute__((ext_vector_type(8))) short short8;
typedef __attribute__((ext_vector_type(8))) unsigned short ushort8;
typedef __attribute__((ext_vector_type(4))) float f32x4;

static constexpr int NN = 50000;   // nodes
static constexpr int NE = 800000;  // edges
static constexpr int SCAN_B = 196; // ceil(NN/256)
static constexpr int NBLK = (NN + 63) / 64;  // 782 blocks of 64 rows

#define MFMA16x16x32 __builtin_amdgcn_mfma_f32_16x16x32_bf16

__device__ __forceinline__ float b2f(unsigned short u){
  unsigned v = ((unsigned)u) << 16;
  return __builtin_bit_cast(float, v);
}
__device__ __forceinline__ unsigned short f2b(float f){
  unsigned x = __builtin_bit_cast(unsigned, f);
  unsigned r = (x + 0x7fffu + ((x >> 16) & 1u)) >> 16;  // RNE
  return (unsigned short)r;
}
__device__ __forceinline__ short8 u2s(ushort8 v){
  return __builtin_bit_cast(short8, v);
}

// ---------------- static device scratch
// Weight layouts are kc-tiled: [kc][Npad][32] so a wave's B-fragment load
// (fixed t) is a CONTIGUOUS 1 KB: lanes (m,q) at byte m*64+q*16.
__device__ __align__(256) int   g_isf32;
__device__ __align__(256) unsigned short g_W1t  [112 * 512];   // 16 tiles of [112][32]
__device__ __align__(256) unsigned short g_W2t  [112 * 128];   // 4 tiles
__device__ __align__(256) unsigned short g_WselfT[112 * 128];
__device__ __align__(256) unsigned short g_WrelT [112 * 128];
__device__ __align__(256) unsigned short g_c1Wt [112 * 128];
__device__ __align__(256) unsigned short g_c2Wt [64 * 128];    // 4 tiles of [64][32]
__device__ __align__(256) unsigned short g_bufA[(size_t)NN * 128];  // holds [N,64] c2 out
__device__ __align__(256) unsigned short g_bufB[(size_t)NN * 128];  // x2
__device__ __align__(256) unsigned short g_bufC[(size_t)NN * 128];  // x3
__device__ __align__(256) int   g_deg[NN];
__device__ __align__(256) int   g_rowptr[NN + 1];
__device__ __align__(256) int   g_cursor[NN];
__device__ __align__(256) int   g_colidx[NE];
__device__ __align__(256) float g_dinv[NN];
__device__ __align__(256) int   g_partial[256];

__device__ __forceinline__ float ld_in(const void* p, int idx, int isf32){
  if (isf32) return ((const float*)p)[idx];
  return b2f(((const unsigned short*)p)[idx]);
}

// ---------------- prep kernels ----------------
__global__ void k_detect_zero(const unsigned short* __restrict__ x){
  if (blockIdx.x == 0){
    __shared__ int sh[256];
    int tid = threadIdx.x;
    int cnt = 0;
    for (int j = 0; j < 16; j++){
      unsigned short h = x[(size_t)(tid * 16 + j) * 2];
      int e = (h >> 7) & 0xFF;
      if (e >= 90 && e <= 160) cnt++;
    }
    sh[tid] = cnt;
    __syncthreads();
    for (int off = 128; off > 0; off >>= 1){
      if (tid < off) sh[tid] += sh[tid + off];
      __syncthreads();
    }
    if (tid == 0) g_isf32 = (sh[0] < 2458) ? 1 : 0;
  } else {
    int i = (blockIdx.x - 1) * 256 + threadIdx.x;
    if (i < NN){ g_deg[i] = 0; g_cursor[i] = 0; }
  }
}

// write into kc-tiled layout: tile (k>>5), row n, slot (k&31)
__device__ __forceinline__ void xp_one(const void* W, unsigned short* Wt, int idx,
                                       int K, int Nc, int Kpad, int Npad, int isf32){
  int n = idx / Kpad;
  int k = idx - n * Kpad;
  float v = 0.f;
  if (n < Nc && k < K) v = ld_in(W, k * Nc + n, isf32);
  Wt[(k >> 5) * (Npad * 32) + n * 32 + (k & 31)] = f2b(v);
}
__global__ void k_transpose_all(const void* W1, const void* W2, const void* Wself,
                                const void* Wrel, const void* c1W, const void* c2W){
  int idx = blockIdx.x * 256 + threadIdx.x;
  const int isf32 = g_isf32;
  if (idx < 57344){ xp_one(W1, g_W1t, idx, 500, 100, 512, 112, isf32); return; }
  idx -= 57344;
  if (idx < 14336){ xp_one(W2,    g_W2t,    idx, 100, 100, 128, 112, isf32); return; }
  idx -= 14336;
  if (idx < 14336){ xp_one(Wself, g_WselfT, idx, 100, 100, 128, 112, isf32); return; }
  idx -= 14336;
  if (idx < 14336){ xp_one(Wrel,  g_WrelT,  idx, 100, 100, 128, 112, isf32); return; }
  idx -= 14336;
  if (idx < 14336){ xp_one(c1W,   g_c1Wt,   idx, 100, 100, 128, 112, isf32); return; }
  idx -= 14336;
  if (idx < 8192){  xp_one(c2W,   g_c2Wt,   idx, 100, 64,  128, 64, isf32); }
}

__global__ void k_deg(const int* __restrict__ tgt){
  int e = blockIdx.x * 256 + threadIdx.x;
  if (e < NE) atomicAdd(&g_deg[tgt[e]], 1);
}
__global__ __launch_bounds__(256) void k_scan1(){
  __shared__ int sh[256];
  int t = threadIdx.x;
  int i = blockIdx.x * 256 + t;
  int val = (i < NN) ? g_deg[i] : 0;
  sh[t] = val; __syncthreads();
#pragma unroll
  for (int off = 1; off < 256; off <<= 1){
    int v = (t >= off) ? sh[t - off] : 0;
    __syncthreads(); sh[t] += v; __syncthreads();
  }
  if (i < NN){ g_rowptr[i] = sh[t] - val; g_dinv[i] = rsqrtf((float)(val + 1)); }
  if (t == 255) g_partial[blockIdx.x] = sh[255];
}
__global__ __launch_bounds__(256) void k_scan2(){
  __shared__ int sh[256];
  int t = threadIdx.x;
  int val = (t < SCAN_B) ? g_partial[t] : 0;
  sh[t] = val; __syncthreads();
#pragma unroll
  for (int off = 1; off < 256; off <<= 1){
    int v = (t >= off) ? sh[t - off] : 0;
    __syncthreads(); sh[t] += v; __syncthreads();
  }
  if (t < SCAN_B) g_partial[t] = sh[t] - val;
  if (t == 255) g_rowptr[NN] = sh[255];
}
__global__ __launch_bounds__(256) void k_scan3(){
  int i = blockIdx.x * 256 + threadIdx.x;
  if (i < NN) g_rowptr[i] += g_partial[blockIdx.x];
}
__global__ void k_fill(const int* __restrict__ src, const int* __restrict__ tgt){
  int e = blockIdx.x * 256 + threadIdx.x;
  if (e >= NE) return;
  int t = tgt[e];
  int pos = g_rowptr[t] + atomicAdd(&g_cursor[t], 1);
  g_colidx[pos] = src[e];
}

// ---------------- shared device helpers ----------------

// Per-wave epilogue over acc[7] (rows q*4+r of a 16-row tile, cols t*16+m).
// DO_LN: bias+LN+ReLU; else bias+ReLU. Writes bf16 rows of stride rstride,
// zero-padding cols 100..127. Rows are stored iff (grow0 + local_row) < NN.
template<int DO_LN>
__device__ __forceinline__ void wave_epi(const f32x4* acc, unsigned short* dst,
    int rstride, int grow0, int lane, int isf32,
    const void* bias, const void* gm, const void* be){
  const int m = lane & 15;
  const int q = lane >> 4;
  float bf_[7], gf_[7], ef_[7];
#pragma unroll
  for (int t = 0; t < 7; t++){
    int col = t * 16 + m;
    bool ok = col < 100;
    bf_[t] = ok ? ld_in(bias, col, isf32) : 0.f;
    if (DO_LN){
      gf_[t] = ok ? ld_in(gm, col, isf32) : 0.f;
      ef_[t] = ok ? ld_in(be, col, isf32) : 0.f;
    }
  }
#pragma unroll
  for (int r = 0; r < 4; r++){
    int rl = q * 4 + r;
    float vals[7], s1 = 0.f, s2 = 0.f;
#pragma unroll
    for (int t = 0; t < 7; t++){
      int col = t * 16 + m;
      float v = (col < 100) ? (acc[t][r] + bf_[t]) : 0.f;
      vals[t] = v; s1 += v; s2 += v * v;
    }
    if (DO_LN){
#pragma unroll
      for (int msk = 1; msk < 16; msk <<= 1){
        s1 += __shfl_xor(s1, msk, 64);
        s2 += __shfl_xor(s2, msk, 64);
      }
      float mu = s1 * 0.01f;
      float var = fmaxf(s2 * 0.01f - mu * mu, 0.f);
      float rstd = rsqrtf(var + 1e-5f);
#pragma unroll
      for (int t = 0; t < 7; t++)
        vals[t] = (vals[t] - mu) * rstd * gf_[t] + ef_[t];
    }
    if (grow0 + rl < NN){
      unsigned short* orow = dst + (size_t)rl * rstride;
#pragma unroll
      for (int t = 0; t < 7; t++){
        int col = t * 16 + m;
        float y = fmaxf(vals[t], 0.f);
        orow[col] = f2b((col < 100) ? y : 0.f);
      }
      orow[112 + m] = 0;
    }
  }
}

// gather-aggregate 64 nodes x 128 cols into bf16 LDS tile (stride 136).
// 4 threads/node, 32 cols each, 4 edges/iter (256 B in flight per thread).
// MODE 0: plain sum; MODE 1: sym-norm + self.
template<int MODE>
__device__ __forceinline__ void agg_tile(const unsigned short* __restrict__ x,
    unsigned short* aggT, int tid, int brow0){
  const int nl = tid >> 2;          // 0..63
  const int c0 = (tid & 3) * 32;    // 0,32,64,96
  const int node = min(brow0 + nl, NN - 1);
  const float wt = (MODE != 0) ? g_dinv[node] : 1.f;
  float a[32];
#pragma unroll
  for (int k = 0; k < 32; k++) a[k] = 0.f;
  const int p0 = g_rowptr[node], p1 = g_rowptr[node + 1];
  for (int p = p0; p < p1; p += 4){
    int s[4]; float wj[4];
#pragma unroll
    for (int j = 0; j < 4; j++){
      bool ok = (p + j) < p1;
      s[j] = ok ? g_colidx[p + j] : node;
      wj[j] = ok ? ((MODE != 0) ? g_dinv[s[j]] * wt : 1.f) : 0.f;
    }
    ushort8 r[4][4];
#pragma unroll
    for (int j = 0; j < 4; j++)
#pragma unroll
      for (int u = 0; u < 4; u++)
        r[j][u] = *reinterpret_cast<const ushort8*>(&x[(size_t)s[j] * 128 + c0 + u * 8]);
#pragma unroll
    for (int j = 0; j < 4; j++)
#pragma unroll
      for (int u = 0; u < 4; u++)
#pragma unroll
        for (int k = 0; k < 8; k++)
          a[u * 8 + k] += wj[j] * b2f((unsigned short)r[j][u][k]);
  }
  if (MODE != 0){
    float ws = wt * wt;
#pragma unroll
    for (int u = 0; u < 4; u++){
      ushort8 sv = *reinterpret_cast<const ushort8*>(&x[(size_t)node * 128 + c0 + u * 8]);
#pragma unroll
      for (int k = 0; k < 8; k++) a[u * 8 + k] += ws * b2f((unsigned short)sv[k]);
    }
  }
  unsigned short* arow = aggT + nl * 136 + c0;
#pragma unroll
  for (int u = 0; u < 4; u++){
    ushort8 o;
#pragma unroll
    for (int k = 0; k < 8; k++) o[k] = f2b(a[u * 8 + k]);
    *reinterpret_cast<ushort8*>(&arow[u * 8]) = o;
  }
}

// ---------------- fused kernels ----------------
// 64 rows/block, 4 waves, each wave owns a full-K 16-row tile.
// All LDS producer/consumer pairs are intra-wave: NO __syncthreads needed.

__global__ __launch_bounds__(256, 3) void k_gemm12(const void* __restrict__ Aext,
    const void* b1, const void* gm1, const void* be1,
    const void* b2, const void* gm2, const void* be2){
  __shared__ unsigned short xT[4][16][136];
  const int tid = threadIdx.x;
  const int w = tid >> 6, lane = tid & 63;
  const int m = lane & 15, q = lane >> 4;
  const int row0 = blockIdx.x * 64 + w * 16;
  const int isf32 = g_isf32;
  const int arow = min(row0 + m, NN - 1);

  // GEMM1: full K=500 (padded 512) per wave; A prefetched fully to registers.
  f32x4 acc[7] = {};
  if (isf32){
    const float* base = (const float*)Aext + (size_t)arow * 500;
#pragma unroll
    for (int h = 0; h < 2; h++){
      f32x4 Ab[16];
#pragma unroll
      for (int kc = 0; kc < 8; kc++){
        int col = (h * 8 + kc) * 32 + q * 8;
        Ab[2 * kc]     = *reinterpret_cast<const f32x4*>(base + min(col, 496));
        Ab[2 * kc + 1] = *reinterpret_cast<const f32x4*>(base + min(col + 4, 496));
      }
      __builtin_amdgcn_sched_barrier(0);
#pragma unroll
      for (int kc = 0; kc < 8; kc++){
        f32x4 lo = Ab[2 * kc], hi = Ab[2 * kc + 1];
        short8 a = {(short)f2b(lo[0]), (short)f2b(lo[1]), (short)f2b(lo[2]), (short)f2b(lo[3]),
                    (short)f2b(hi[0]), (short)f2b(hi[1]), (short)f2b(hi[2]), (short)f2b(hi[3])};
        const unsigned short* bp = g_W1t + (h * 8 + kc) * 3584 + m * 32 + q * 8;
#pragma unroll
        for (int t = 0; t < 7; t++){
          short8 b = *reinterpret_cast<const short8*>(bp + t * 512);
          acc[t] = MFMA16x16x32(a, b, acc[t], 0, 0, 0);
        }
      }
    }
  } else {
    const unsigned short* base = (const unsigned short*)Aext + (size_t)arow * 500;
    ushort4 Ab[32];
#pragma unroll
    for (int kc = 0; kc < 16; kc++){
      int col = kc * 32 + q * 8;
      Ab[2 * kc]     = *reinterpret_cast<const ushort4*>(base + min(col, 496));
      Ab[2 * kc + 1] = *reinterpret_cast<const ushort4*>(base + min(col + 4, 496));
    }
    __builtin_amdgcn_sched_barrier(0);
#pragma unroll
    for (int kc = 0; kc < 16; kc++){
      ushort4 lo = Ab[2 * kc], hi = Ab[2 * kc + 1];
      short8 a = {(short)lo.x, (short)lo.y, (short)lo.z, (short)lo.w,
                  (short)hi.x, (short)hi.y, (short)hi.z, (short)hi.w};
      const unsigned short* bp = g_W1t + kc * 3584 + m * 32 + q * 8;
#pragma unroll
      for (int t = 0; t < 7; t++){
        short8 b = *reinterpret_cast<const short8*>(bp + t * 512);
        acc[t] = MFMA16x16x32(a, b, acc[t], 0, 0, 0);
      }
    }
  }
  // LN1 + ReLU -> per-wave bf16 LDS tile (intra-wave: no barrier)
  wave_epi<1>(acc, &xT[w][0][0], 136, 0, lane, isf32, b1, gm1, be1);

  // GEMM2: K=100 (padded 128) per wave
  f32x4 acc2[7] = {};
#pragma unroll
  for (int kc = 0; kc < 4; kc++){
    int k0 = kc * 32 + q * 8;
    short8 a = u2s(*reinterpret_cast<const ushort8*>(&xT[w][m][k0]));
    const unsigned short* bp = g_W2t + kc * 3584 + m * 32 + q * 8;
#pragma unroll
    for (int t = 0; t < 7; t++){
      short8 b = *reinterpret_cast<const short8*>(bp + t * 512);
      acc2[t] = MFMA16x16x32(a, b, acc2[t], 0, 0, 0);
    }
  }
  wave_epi<1>(acc2, g_bufB + (size_t)row0 * 128, 128, row0, lane, isf32, b2, gm2, be2);
}

// RGCN: agg(bufB)->LDS, dual GEMM (bufB@Wself + agg@Wrel), bias+ReLU -> bufC.
__global__ __launch_bounds__(256, 3) void k_rgcn_f(const void* rb){
  __shared__ unsigned short aggT[64 * 136];
  const int tid = threadIdx.x;
  const int brow0 = blockIdx.x * 64;
  agg_tile<0>(g_bufB, aggT, tid, brow0);  // wave w writes rows 16w..16w+15 only

  const int w = tid >> 6, lane = tid & 63;
  const int m = lane & 15, q = lane >> 4;
  const int row0 = brow0 + w * 16;
  const int arow = min(row0 + m, NN - 1);
  const int isf32 = g_isf32;
  f32x4 acc[7] = {};
#pragma unroll
  for (int kc = 0; kc < 4; kc++){
    int k0 = kc * 32 + q * 8;
    short8 a1 = u2s(*reinterpret_cast<const ushort8*>(&g_bufB[(size_t)arow * 128 + k0]));
    const unsigned short* bp1 = g_WselfT + kc * 3584 + m * 32 + q * 8;
#pragma unroll
    for (int t = 0; t < 7; t++){
      short8 b = *reinterpret_cast<const short8*>(bp1 + t * 512);
      acc[t] = MFMA16x16x32(a1, b, acc[t], 0, 0, 0);
    }
    short8 a2 = u2s(*reinterpret_cast<const ushort8*>(&aggT[(w * 16 + m) * 136 + k0]));
    const unsigned short* bp2 = g_WrelT + kc * 3584 + m * 32 + q * 8;
#pragma unroll
    for (int t = 0; t < 7; t++){
      short8 b = *reinterpret_cast<const short8*>(bp2 + t * 512);
      acc[t] = MFMA16x16x32(a2, b, acc[t], 0, 0, 0);
    }
  }
  wave_epi<0>(acc, g_bufC + (size_t)row0 * 128, 128, row0, lane, isf32, rb, nullptr, nullptr);
}

// conv1+conv2: aggnorm(bufC)->LDS, c1 GEMM+bias+ReLU->LDS (tile reuse),
// c2 GEMM -> bufA[N,64]. All tile traffic is intra-wave.
__global__ __launch_bounds__(256, 3) void k_conv_f(const void* c1b){
  __shared__ unsigned short aggT[64 * 136];
  const int tid = threadIdx.x;
  const int brow0 = blockIdx.x * 64;
  agg_tile<1>(g_bufC, aggT, tid, brow0);

  const int w = tid >> 6, lane = tid & 63;
  const int m = lane & 15, q = lane >> 4;
  const int row0 = brow0 + w * 16;
  const int isf32 = g_isf32;
  unsigned short* tile = aggT + w * 16 * 136;

  f32x4 acc[7] = {};
#pragma unroll
  for (int kc = 0; kc < 4; kc++){
    int k0 = kc * 32 + q * 8;
    short8 a = u2s(*reinterpret_cast<const ushort8*>(&tile[m * 136 + k0]));
    const unsigned short* bp = g_c1Wt + kc * 3584 + m * 32 + q * 8;
#pragma unroll
    for (int t = 0; t < 7; t++){
      short8 b = *reinterpret_cast<const short8*>(bp + t * 512);
      acc[t] = MFMA16x16x32(a, b, acc[t], 0, 0, 0);
    }
  }
  wave_epi<0>(acc, tile, 136, 0, lane, isf32, c1b, nullptr, nullptr);  // tile reused as x4

  // c2: [16,100] @ c2Wt -> [16,64] (bias + log_softmax applied downstream)
  f32x4 acc2[4] = {};
#pragma unroll
  for (int kc = 0; kc < 4; kc++){
    int k0 = kc * 32 + q * 8;
    short8 a = u2s(*reinterpret_cast<const ushort8*>(&tile[m * 136 + k0]));
    const unsigned short* bp = g_c2Wt + kc * 2048 + m * 32 + q * 8;
#pragma unroll
    for (int t = 0; t < 4; t++){
      short8 b = *reinterpret_cast<const short8*>(bp + t * 512);
      acc2[t] = MFMA16x16x32(a, b, acc2[t], 0, 0, 0);
    }
  }
#pragma unroll
  for (int r = 0; r < 4; r++){
    int row = row0 + q * 4 + r;
    if (row < NN){
      unsigned short* orow = g_bufA + (size_t)row * 64;
#pragma unroll
      for (int t = 0; t < 4; t++) orow[t * 16 + m] = f2b(acc2[t][r]);
    }
  }
}

// conv2 aggregate (64-col rows in bufA) + bias + log_softmax -> out
__global__ __launch_bounds__(256) void k_agg_lsm(const void* __restrict__ bias,
                                                 void* __restrict__ outv){
  const int isf32 = g_isf32;
  int node = blockIdx.x * 32 + (threadIdx.x >> 3);
  if (node >= NN) return;
  const int c8 = (threadIdx.x & 7) * 8;
  float wt = g_dinv[node];
  float a[4][8];
#pragma unroll
  for (int j = 0; j < 4; j++)
#pragma unroll
    for (int k = 0; k < 8; k++) a[j][k] = 0.f;
  int p0 = g_rowptr[node], p1 = g_rowptr[node + 1];
  for (int p = p0; p < p1; p += 8){
    int sj[8]; float wj[8];
#pragma unroll
    for (int j = 0; j < 8; j++){
      bool ok = (p + j) < p1;
      sj[j] = ok ? g_colidx[p + j] : node;
      wj[j] = ok ? g_dinv[sj[j]] * wt : 0.f;
    }
    ushort8 r[8];
#pragma unroll
    for (int j = 0; j < 8; j++)
      r[j] = *reinterpret_cast<const ushort8*>(&g_bufA[(size_t)sj[j] * 64 + c8]);
#pragma unroll
    for (int j = 0; j < 8; j++)
#pragma unroll
      for (int k = 0; k < 8; k++) a[j & 3][k] += wj[j] * b2f((unsigned short)r[j][k]);
  }
  float ws = wt * wt;
  ushort8 sv = *reinterpret_cast<const ushort8*>(&g_bufA[(size_t)node * 64 + c8]);
#pragma unroll
  for (int k = 0; k < 8; k++) a[0][k] += ws * b2f((unsigned short)sv[k]);

  float v[8], mx = -1e30f;
#pragma unroll
  for (int k = 0; k < 8; k++){
    v[k] = a[0][k] + a[1][k] + a[2][k] + a[3][k] + ld_in(bias, c8 + k, isf32);
    mx = fmaxf(mx, v[k]);
  }
#pragma unroll
  for (int msk = 1; msk < 8; msk <<= 1) mx = fmaxf(mx, __shfl_xor(mx, msk, 64));
  float se = 0.f;
#pragma unroll
  for (int k = 0; k < 8; k++) se += expf(v[k] - mx);
#pragma unroll
  for (int msk = 1; msk < 8; msk <<= 1) se += __shfl_xor(se, msk, 64);
  float lse = logf(se);
  size_t ro = (size_t)node * 64 + c8;
  if (isf32){
    float* o = (float*)outv + ro;
#pragma unroll
    for (int k = 0; k < 8; k++) o[k] = v[k] - mx - lse;
  } else {
    unsigned short* o = (unsigned short*)outv + ro;
#pragma unroll
    for (int k = 0; k < 8; k++) o[k] = f2b(v[k] - mx - lse);
  }
}

extern "C" void kernel_launch(void* const* d_in, const int* in_sizes, int n_in,
                              void* d_out, int out_size, void* d_ws, size_t ws_size,
                              hipStream_t stream){
  (void)in_sizes; (void)n_in; (void)out_size; (void)d_ws; (void)ws_size;
  const void* data_x = d_in[0];
  const int* ei = (const int*)d_in[1];
  const int* src = ei;
  const int* tgt = ei + NE;
  const void *W1 = d_in[3], *b1 = d_in[4], *gm1 = d_in[5], *be1 = d_in[6];
  const void *W2 = d_in[7], *b2 = d_in[8], *gm2 = d_in[9], *be2 = d_in[10];
  const void *Wrel = d_in[11], *Wself = d_in[12], *rb = d_in[13];
  const void *c1W = d_in[14], *c1b = d_in[15];
  const void *c2W = d_in[16], *c2b = d_in[17];

  k_detect_zero<<<1 + (NN + 255) / 256, 256, 0, stream>>>((const unsigned short*)data_x);
  k_transpose_all<<<(122880 + 255) / 256, 256, 0, stream>>>(W1, W2, Wself, Wrel, c1W, c2W);

  k_deg<<<(NE + 255) / 256, 256, 0, stream>>>(tgt);
  k_scan1<<<SCAN_B, 256, 0, stream>>>();
  k_scan2<<<1, 256, 0, stream>>>();
  k_scan3<<<SCAN_B, 256, 0, stream>>>();
  k_fill<<<(NE + 255) / 256, 256, 0, stream>>>(src, tgt);

  k_gemm12<<<NBLK, 256, 0, stream>>>(data_x, b1, gm1, be1, b2, gm2, be2); // -> bufB
  k_rgcn_f<<<NBLK, 256, 0, stream>>>(rb);                                 // bufB -> bufC
  k_conv_f<<<NBLK, 256, 0, stream>>>(c1b);                                // bufC -> bufA[N,64]
  k_agg_lsm<<<(NN + 31) / 32, 256, 0, stream>>>(c2b, d_out);              // bufA -> out
}

// Round 3
// 438.089 us; speedup vs baseline: 1.1123x; 1.0918x over previous
//
#include <hip/hip_runtime.h>
#include <hip/hip_bf16.h>

typedef __attribute__((ext_vector_type(8))) short short8;
typedef __attribute__((ext_vector_type(8))) unsigned short ushort8;
typedef __attribute__((ext_vector_type(4))) float f32x4;

static constexpr int NN = 50000;   // nodes
static constexpr int NE = 800000;  // edges
static constexpr int SCAN_B = 196; // ceil(NN/256)
static constexpr int NBLK = (NN + 63) / 64;  // 782 blocks of 64 rows

#define MFMA16x16x32 __builtin_amdgcn_mfma_f32_16x16x32_bf16

__device__ __forceinline__ float b2f(unsigned short u){
  unsigned v = ((unsigned)u) << 16;
  return __builtin_bit_cast(float, v);
}
__device__ __forceinline__ unsigned short f2b(float f){
  unsigned x = __builtin_bit_cast(unsigned, f);
  unsigned r = (x + 0x7fffu + ((x >> 16) & 1u)) >> 16;  // RNE
  return (unsigned short)r;
}
__device__ __forceinline__ short8 u2s(ushort8 v){
  return __builtin_bit_cast(short8, v);
}

// ---------------- static device scratch
// Weight layouts are kc-tiled: [kc][Npad][32] so a wave's B-fragment load
// (fixed t) is a CONTIGUOUS 1 KB: lanes (m,q) at byte m*64+q*16.
// g_W1t padded +512 shorts so 8-KB staging reads never run off the end.
__device__ __align__(256) int   g_isf32;
__device__ __align__(256) unsigned short g_W1t  [112 * 512 + 512]; // 16 tiles of [112][32] (+pad)
__device__ __align__(256) unsigned short g_W2t  [112 * 128];   // 4 tiles
__device__ __align__(256) unsigned short g_WselfT[112 * 128];
__device__ __align__(256) unsigned short g_WrelT [112 * 128];
__device__ __align__(256) unsigned short g_c1Wt [112 * 128];
__device__ __align__(256) unsigned short g_c2Wt [64 * 128];    // 4 tiles of [64][32]
__device__ __align__(256) unsigned short g_bufA[(size_t)NN * 128];  // holds [N,64] c2 out
__device__ __align__(256) unsigned short g_bufB[(size_t)NN * 128];  // x2
__device__ __align__(256) unsigned short g_bufC[(size_t)NN * 128];  // x3
__device__ __align__(256) int   g_deg[NN];
__device__ __align__(256) int   g_rowptr[NN + 1];
__device__ __align__(256) int   g_colidx[NE];
__device__ __align__(256) int   g_epos[NE];
__device__ __align__(256) float g_dinv[NN];
__device__ __align__(256) int   g_partial[256];

__device__ __forceinline__ float ld_in(const void* p, int idx, int isf32){
  if (isf32) return ((const float*)p)[idx];
  return b2f(((const unsigned short*)p)[idx]);
}

// ---------------- prep kernels ----------------
__global__ void k_detect_zero(const unsigned short* __restrict__ x){
  if (blockIdx.x == 0){
    __shared__ int sh[256];
    int tid = threadIdx.x;
    int cnt = 0;
    for (int j = 0; j < 16; j++){
      unsigned short h = x[(size_t)(tid * 16 + j) * 2];
      int e = (h >> 7) & 0xFF;
      if (e >= 90 && e <= 160) cnt++;
    }
    sh[tid] = cnt;
    __syncthreads();
    for (int off = 128; off > 0; off >>= 1){
      if (tid < off) sh[tid] += sh[tid + off];
      __syncthreads();
    }
    if (tid == 0) g_isf32 = (sh[0] < 2458) ? 1 : 0;
  } else {
    int i = (blockIdx.x - 1) * 256 + threadIdx.x;
    if (i < NN) g_deg[i] = 0;
  }
}

// write into kc-tiled layout: tile (k>>5), row n, slot (k&31)
__device__ __forceinline__ void xp_one(const void* W, unsigned short* Wt, int idx,
                                       int K, int Nc, int Kpad, int Npad, int isf32){
  int n = idx / Kpad;
  int k = idx - n * Kpad;
  float v = 0.f;
  if (n < Nc && k < K) v = ld_in(W, k * Nc + n, isf32);
  Wt[(k >> 5) * (Npad * 32) + n * 32 + (k & 31)] = f2b(v);
}
__global__ void k_transpose_all(const void* W1, const void* W2, const void* Wself,
                                const void* Wrel, const void* c1W, const void* c2W){
  int idx = blockIdx.x * 256 + threadIdx.x;
  const int isf32 = g_isf32;
  if (idx < 57344){ xp_one(W1, g_W1t, idx, 500, 100, 512, 112, isf32); return; }
  idx -= 57344;
  if (idx < 14336){ xp_one(W2,    g_W2t,    idx, 100, 100, 128, 112, isf32); return; }
  idx -= 14336;
  if (idx < 14336){ xp_one(Wself, g_WselfT, idx, 100, 100, 128, 112, isf32); return; }
  idx -= 14336;
  if (idx < 14336){ xp_one(Wrel,  g_WrelT,  idx, 100, 100, 128, 112, isf32); return; }
  idx -= 14336;
  if (idx < 14336){ xp_one(c1W,   g_c1Wt,   idx, 100, 100, 128, 112, isf32); return; }
  idx -= 14336;
  if (idx < 8192){  xp_one(c2W,   g_c2Wt,   idx, 100, 64,  128, 64, isf32); }
}

// deg count; returned old value IS the edge's within-bucket slot -> no
// second atomic pass needed in k_fill.
__global__ void k_deg(const int* __restrict__ tgt){
  int e = blockIdx.x * 256 + threadIdx.x;
  if (e < NE) g_epos[e] = atomicAdd(&g_deg[tgt[e]], 1);
}
__global__ __launch_bounds__(256) void k_scan1(){
  __shared__ int sh[256];
  int t = threadIdx.x;
  int i = blockIdx.x * 256 + t;
  int val = (i < NN) ? g_deg[i] : 0;
  sh[t] = val; __syncthreads();
#pragma unroll
  for (int off = 1; off < 256; off <<= 1){
    int v = (t >= off) ? sh[t - off] : 0;
    __syncthreads(); sh[t] += v; __syncthreads();
  }
  if (i < NN){ g_rowptr[i] = sh[t] - val; g_dinv[i] = rsqrtf((float)(val + 1)); }
  if (t == 255) g_partial[blockIdx.x] = sh[255];
}
__global__ __launch_bounds__(256) void k_scan2(){
  __shared__ int sh[256];
  int t = threadIdx.x;
  int val = (t < SCAN_B) ? g_partial[t] : 0;
  sh[t] = val; __syncthreads();
#pragma unroll
  for (int off = 1; off < 256; off <<= 1){
    int v = (t >= off) ? sh[t - off] : 0;
    __syncthreads(); sh[t] += v; __syncthreads();
  }
  if (t < SCAN_B) g_partial[t] = sh[t] - val;
  if (t == 255) g_rowptr[NN] = sh[255];
}
__global__ __launch_bounds__(256) void k_scan3(){
  int i = blockIdx.x * 256 + threadIdx.x;
  if (i < NN) g_rowptr[i] += g_partial[blockIdx.x];
}
__global__ void k_fill(const int* __restrict__ src, const int* __restrict__ tgt){
  int e = blockIdx.x * 256 + threadIdx.x;
  if (e >= NE) return;
  g_colidx[g_rowptr[tgt[e]] + g_epos[e]] = src[e];
}

// ---------------- shared device helpers ----------------

// Per-wave epilogue over acc[7] (rows q*4+r of a 16-row tile, cols t*16+m).
// DO_LN: bias+LN+ReLU; else bias+ReLU. Writes bf16 rows of stride rstride,
// zero-padding cols 100..127. Rows are stored iff (grow0 + local_row) < NN.
template<int DO_LN>
__device__ __forceinline__ void wave_epi(const f32x4* acc, unsigned short* dst,
    int rstride, int grow0, int lane, int isf32,
    const void* bias, const void* gm, const void* be){
  const int m = lane & 15;
  const int q = lane >> 4;
  float bf_[7], gf_[7], ef_[7];
#pragma unroll
  for (int t = 0; t < 7; t++){
    int col = t * 16 + m;
    bool ok = col < 100;
    bf_[t] = ok ? ld_in(bias, col, isf32) : 0.f;
    if (DO_LN){
      gf_[t] = ok ? ld_in(gm, col, isf32) : 0.f;
      ef_[t] = ok ? ld_in(be, col, isf32) : 0.f;
    }
  }
#pragma unroll
  for (int r = 0; r < 4; r++){
    int rl = q * 4 + r;
    float vals[7], s1 = 0.f, s2 = 0.f;
#pragma unroll
    for (int t = 0; t < 7; t++){
      int col = t * 16 + m;
      float v = (col < 100) ? (acc[t][r] + bf_[t]) : 0.f;
      vals[t] = v; s1 += v; s2 += v * v;
    }
    if (DO_LN){
#pragma unroll
      for (int msk = 1; msk < 16; msk <<= 1){
        s1 += __shfl_xor(s1, msk, 64);
        s2 += __shfl_xor(s2, msk, 64);
      }
      float mu = s1 * 0.01f;
      float var = fmaxf(s2 * 0.01f - mu * mu, 0.f);
      float rstd = rsqrtf(var + 1e-5f);
#pragma unroll
      for (int t = 0; t < 7; t++)
        vals[t] = (vals[t] - mu) * rstd * gf_[t] + ef_[t];
    }
    if (grow0 + rl < NN){
      unsigned short* orow = dst + (size_t)rl * rstride;
#pragma unroll
      for (int t = 0; t < 7; t++){
        int col = t * 16 + m;
        float y = fmaxf(vals[t], 0.f);
        orow[col] = f2b((col < 100) ? y : 0.f);
      }
      orow[112 + m] = 0;
    }
  }
}

// gather-aggregate 64 nodes x 128 cols into bf16 LDS tile (stride 136).
// 4 threads/node, 32 cols each, 4 edges/iter (256 B in flight per thread).
// MODE 0: plain sum; MODE 1: sym-norm + self.
template<int MODE>
__device__ __forceinline__ void agg_tile(const unsigned short* __restrict__ x,
    unsigned short* aggT, int tid, int brow0){
  const int nl = tid >> 2;          // 0..63
  const int c0 = (tid & 3) * 32;    // 0,32,64,96
  const int node = min(brow0 + nl, NN - 1);
  const float wt = (MODE != 0) ? g_dinv[node] : 1.f;
  float a[32];
#pragma unroll
  for (int k = 0; k < 32; k++) a[k] = 0.f;
  const int p0 = g_rowptr[node], p1 = g_rowptr[node + 1];
  for (int p = p0; p < p1; p += 4){
    int s[4]; float wj[4];
#pragma unroll
    for (int j = 0; j < 4; j++){
      bool ok = (p + j) < p1;
      s[j] = ok ? g_colidx[p + j] : node;
      wj[j] = ok ? ((MODE != 0) ? g_dinv[s[j]] * wt : 1.f) : 0.f;
    }
    ushort8 r[4][4];
#pragma unroll
    for (int j = 0; j < 4; j++)
#pragma unroll
      for (int u = 0; u < 4; u++)
        r[j][u] = *reinterpret_cast<const ushort8*>(&x[(size_t)s[j] * 128 + c0 + u * 8]);
#pragma unroll
    for (int j = 0; j < 4; j++)
#pragma unroll
      for (int u = 0; u < 4; u++)
#pragma unroll
        for (int k = 0; k < 8; k++)
          a[u * 8 + k] += wj[j] * b2f((unsigned short)r[j][u][k]);
  }
  if (MODE != 0){
    float ws = wt * wt;
#pragma unroll
    for (int u = 0; u < 4; u++){
      ushort8 sv = *reinterpret_cast<const ushort8*>(&x[(size_t)node * 128 + c0 + u * 8]);
#pragma unroll
      for (int k = 0; k < 8; k++) a[u * 8 + k] += ws * b2f((unsigned short)sv[k]);
    }
  }
  unsigned short* arow = aggT + nl * 136 + c0;
#pragma unroll
  for (int u = 0; u < 4; u++){
    ushort8 o;
#pragma unroll
    for (int k = 0; k < 8; k++) o[k] = f2b(a[u * 8 + k]);
    *reinterpret_cast<ushort8*>(&arow[u * 8]) = o;
  }
}

// ---------------- fused kernels ----------------
// k_gemm12: 64 rows/block, 4 waves x 16 rows. W1 kc-tiles (7 KB each) are
// cooperatively staged into LDS via global_load_lds, double-buffered,
// one barrier per kc (2-phase pipeline). A is prefetched+converted to bf16
// fragments in registers before the loop.

__global__ __launch_bounds__(256, 3) void k_gemm12(const void* __restrict__ Aext,
    const void* b1, const void* gm1, const void* be1,
    const void* b2, const void* gm2, const void* be2){
  __shared__ unsigned short xT[4][16][136];   // 17408 B
  __shared__ unsigned short Wst[2][4096];     // 16384 B, 2 x 8-KB stage buffers
  const int tid = threadIdx.x;
  const int w = tid >> 6, lane = tid & 63;
  const int m = lane & 15, q = lane >> 4;
  const int row0 = blockIdx.x * 64 + w * 16;
  const int isf32 = g_isf32;
  const int arow = min(row0 + m, NN - 1);

  // ---- A prefetch: convert to 16 bf16 fragments (64 VGPR), 2 chunks of 8
  short8 afrag[16];
  if (isf32){
    const float* base = (const float*)Aext + (size_t)arow * 500;
#pragma unroll
    for (int h = 0; h < 2; h++){
      f32x4 Ab[16];
#pragma unroll
      for (int kc = 0; kc < 8; kc++){
        int col = (h * 8 + kc) * 32 + q * 8;
        Ab[2 * kc]     = *reinterpret_cast<const f32x4*>(base + min(col, 496));
        Ab[2 * kc + 1] = *reinterpret_cast<const f32x4*>(base + min(col + 4, 496));
      }
#pragma unroll
      for (int kc = 0; kc < 8; kc++){
        f32x4 lo = Ab[2 * kc], hi = Ab[2 * kc + 1];
        afrag[h * 8 + kc] = short8{
          (short)f2b(lo[0]), (short)f2b(lo[1]), (short)f2b(lo[2]), (short)f2b(lo[3]),
          (short)f2b(hi[0]), (short)f2b(hi[1]), (short)f2b(hi[2]), (short)f2b(hi[3])};
      }
    }
  } else {
    const unsigned short* base = (const unsigned short*)Aext + (size_t)arow * 500;
#pragma unroll
    for (int h = 0; h < 2; h++){
      ushort4 Ab[16];
#pragma unroll
      for (int kc = 0; kc < 8; kc++){
        int col = (h * 8 + kc) * 32 + q * 8;
        Ab[2 * kc]     = *reinterpret_cast<const ushort4*>(base + min(col, 496));
        Ab[2 * kc + 1] = *reinterpret_cast<const ushort4*>(base + min(col + 4, 496));
      }
#pragma unroll
      for (int kc = 0; kc < 8; kc++){
        ushort4 lo = Ab[2 * kc], hi = Ab[2 * kc + 1];
        afrag[h * 8 + kc] = short8{
          (short)lo.x, (short)lo.y, (short)lo.z, (short)lo.w,
          (short)hi.x, (short)hi.y, (short)hi.z, (short)hi.w};
      }
    }
  }

  // ---- prologue: stage kc=0 tile into Wst[0] (each wave stages 2 KB)
  {
    const unsigned short* srcp = g_W1t;
#pragma unroll
    for (int j = 0; j < 2; j++){
      int soff = (w * 2 + j) * 512;   // shorts
      __builtin_amdgcn_global_load_lds(
        (const __attribute__((address_space(1))) void*)(srcp + soff + lane * 8),
        (__attribute__((address_space(3))) void*)(&Wst[0][soff]), 16, 0, 0);
    }
  }
  __syncthreads();

  // ---- GEMM1 main loop: stage next tile, compute current from LDS
  f32x4 acc[7] = {};
#pragma unroll
  for (int kc = 0; kc < 16; kc++){
    const int cur = kc & 1;
    if (kc < 15){
      const unsigned short* srcp = g_W1t + (kc + 1) * 3584;
#pragma unroll
      for (int j = 0; j < 2; j++){
        int soff = (w * 2 + j) * 512;
        __builtin_amdgcn_global_load_lds(
          (const __attribute__((address_space(1))) void*)(srcp + soff + lane * 8),
          (__attribute__((address_space(3))) void*)(&Wst[cur ^ 1][soff]), 16, 0, 0);
      }
    }
    const unsigned short* bp = &Wst[cur][m * 32 + q * 8];
#pragma unroll
    for (int t = 0; t < 7; t++){
      short8 b = *reinterpret_cast<const short8*>(bp + t * 512);
      acc[t] = MFMA16x16x32(afrag[kc], b, acc[t], 0, 0, 0);
    }
    __syncthreads();   // staged tile ready; all reads of cur done
  }

  // LN1 + ReLU -> per-wave bf16 LDS tile (intra-wave)
  wave_epi<1>(acc, &xT[w][0][0], 136, 0, lane, isf32, b1, gm1, be1);

  // GEMM2: K=100 (padded 128) per wave; W2t from L2 (hot, reused 4x/block)
  f32x4 acc2[7] = {};
#pragma unroll
  for (int kc = 0; kc < 4; kc++){
    int k0 = kc * 32 + q * 8;
    short8 a = u2s(*reinterpret_cast<const ushort8*>(&xT[w][m][k0]));
    const unsigned short* bp = g_W2t + kc * 3584 + m * 32 + q * 8;
#pragma unroll
    for (int t = 0; t < 7; t++){
      short8 b = *reinterpret_cast<const short8*>(bp + t * 512);
      acc2[t] = MFMA16x16x32(a, b, acc2[t], 0, 0, 0);
    }
  }
  wave_epi<1>(acc2, g_bufB + (size_t)row0 * 128, 128, row0, lane, isf32, b2, gm2, be2);
}

// RGCN: agg(bufB)->LDS, dual GEMM (bufB@Wself + agg@Wrel), bias+ReLU -> bufC.
// All LDS producer/consumer pairs are intra-wave: no barriers.
__global__ __launch_bounds__(256, 3) void k_rgcn_f(const void* rb){
  __shared__ unsigned short aggT[64 * 136];
  const int tid = threadIdx.x;
  const int brow0 = blockIdx.x * 64;
  agg_tile<0>(g_bufB, aggT, tid, brow0);  // wave w writes rows 16w..16w+15 only

  const int w = tid >> 6, lane = tid & 63;
  const int m = lane & 15, q = lane >> 4;
  const int row0 = brow0 + w * 16;
  const int arow = min(row0 + m, NN - 1);
  const int isf32 = g_isf32;
  f32x4 acc[7] = {};
#pragma unroll
  for (int kc = 0; kc < 4; kc++){
    int k0 = kc * 32 + q * 8;
    short8 a1 = u2s(*reinterpret_cast<const ushort8*>(&g_bufB[(size_t)arow * 128 + k0]));
    const unsigned short* bp1 = g_WselfT + kc * 3584 + m * 32 + q * 8;
#pragma unroll
    for (int t = 0; t < 7; t++){
      short8 b = *reinterpret_cast<const short8*>(bp1 + t * 512);
      acc[t] = MFMA16x16x32(a1, b, acc[t], 0, 0, 0);
    }
    short8 a2 = u2s(*reinterpret_cast<const ushort8*>(&aggT[(w * 16 + m) * 136 + k0]));
    const unsigned short* bp2 = g_WrelT + kc * 3584 + m * 32 + q * 8;
#pragma unroll
    for (int t = 0; t < 7; t++){
      short8 b = *reinterpret_cast<const short8*>(bp2 + t * 512);
      acc[t] = MFMA16x16x32(a2, b, acc[t], 0, 0, 0);
    }
  }
  wave_epi<0>(acc, g_bufC + (size_t)row0 * 128, 128, row0, lane, isf32, rb, nullptr, nullptr);
}

// conv1+conv2: aggnorm(bufC)->LDS, c1 GEMM+bias+ReLU->LDS (tile reuse),
// c2 GEMM -> bufA[N,64]. All tile traffic is intra-wave.
__global__ __launch_bounds__(256, 3) void k_conv_f(const void* c1b){
  __shared__ unsigned short aggT[64 * 136];
  const int tid = threadIdx.x;
  const int brow0 = blockIdx.x * 64;
  agg_tile<1>(g_bufC, aggT, tid, brow0);

  const int w = tid >> 6, lane = tid & 63;
  const int m = lane & 15, q = lane >> 4;
  const int row0 = brow0 + w * 16;
  const int isf32 = g_isf32;
  unsigned short* tile = aggT + w * 16 * 136;

  f32x4 acc[7] = {};
#pragma unroll
  for (int kc = 0; kc < 4; kc++){
    int k0 = kc * 32 + q * 8;
    short8 a = u2s(*reinterpret_cast<const ushort8*>(&tile[m * 136 + k0]));
    const unsigned short* bp = g_c1Wt + kc * 3584 + m * 32 + q * 8;
#pragma unroll
    for (int t = 0; t < 7; t++){
      short8 b = *reinterpret_cast<const short8*>(bp + t * 512);
      acc[t] = MFMA16x16x32(a, b, acc[t], 0, 0, 0);
    }
  }
  wave_epi<0>(acc, tile, 136, 0, lane, isf32, c1b, nullptr, nullptr);  // tile reused as x4

  // c2: [16,100] @ c2Wt -> [16,64] (bias + log_softmax applied downstream)
  f32x4 acc2[4] = {};
#pragma unroll
  for (int kc = 0; kc < 4; kc++){
    int k0 = kc * 32 + q * 8;
    short8 a = u2s(*reinterpret_cast<const ushort8*>(&tile[m * 136 + k0]));
    const unsigned short* bp = g_c2Wt + kc * 2048 + m * 32 + q * 8;
#pragma unroll
    for (int t = 0; t < 4; t++){
      short8 b = *reinterpret_cast<const short8*>(bp + t * 512);
      acc2[t] = MFMA16x16x32(a, b, acc2[t], 0, 0, 0);
    }
  }
#pragma unroll
  for (int r = 0; r < 4; r++){
    int row = row0 + q * 4 + r;
    if (row < NN){
      unsigned short* orow = g_bufA + (size_t)row * 64;
#pragma unroll
      for (int t = 0; t < 4; t++) orow[t * 16 + m] = f2b(acc2[t][r]);
    }
  }
}

// conv2 aggregate (64-col rows in bufA) + bias + log_softmax -> out
__global__ __launch_bounds__(256) void k_agg_lsm(const void* __restrict__ bias,
                                                 void* __restrict__ outv){
  const int isf32 = g_isf32;
  int node = blockIdx.x * 32 + (threadIdx.x >> 3);
  if (node >= NN) return;
  const int c8 = (threadIdx.x & 7) * 8;
  float wt = g_dinv[node];
  float a[4][8];
#pragma unroll
  for (int j = 0; j < 4; j++)
#pragma unroll
    for (int k = 0; k < 8; k++) a[j][k] = 0.f;
  int p0 = g_rowptr[node], p1 = g_rowptr[node + 1];
  for (int p = p0; p < p1; p += 8){
    int sj[8]; float wj[8];
#pragma unroll
    for (int j = 0; j < 8; j++){
      bool ok = (p + j) < p1;
      sj[j] = ok ? g_colidx[p + j] : node;
      wj[j] = ok ? g_dinv[sj[j]] * wt : 0.f;
    }
    ushort8 r[8];
#pragma unroll
    for (int j = 0; j < 8; j++)
      r[j] = *reinterpret_cast<const ushort8*>(&g_bufA[(size_t)sj[j] * 64 + c8]);
#pragma unroll
    for (int j = 0; j < 8; j++)
#pragma unroll
      for (int k = 0; k < 8; k++) a[j & 3][k] += wj[j] * b2f((unsigned short)r[j][k]);
  }
  float ws = wt * wt;
  ushort8 sv = *reinterpret_cast<const ushort8*>(&g_bufA[(size_t)node * 64 + c8]);
#pragma unroll
  for (int k = 0; k < 8; k++) a[0][k] += ws * b2f((unsigned short)sv[k]);

  float v[8], mx = -1e30f;
#pragma unroll
  for (int k = 0; k < 8; k++){
    v[k] = a[0][k] + a[1][k] + a[2][k] + a[3][k] + ld_in(bias, c8 + k, isf32);
    mx = fmaxf(mx, v[k]);
  }
#pragma unroll
  for (int msk = 1; msk < 8; msk <<= 1) mx = fmaxf(mx, __shfl_xor(mx, msk, 64));
  float se = 0.f;
#pragma unroll
  for (int k = 0; k < 8; k++) se += expf(v[k] - mx);
#pragma unroll
  for (int msk = 1; msk < 8; msk <<= 1) se += __shfl_xor(se, msk, 64);
  float lse = logf(se);
  size_t ro = (size_t)node * 64 + c8;
  if (isf32){
    float* o = (float*)outv + ro;
#pragma unroll
    for (int k = 0; k < 8; k++) o[k] = v[k] - mx - lse;
  } else {
    unsigned short* o = (unsigned short*)outv + ro;
#pragma unroll
    for (int k = 0; k < 8; k++) o[k] = f2b(v[k] - mx - lse);
  }
}

extern "C" void kernel_launch(void* const* d_in, const int* in_sizes, int n_in,
                              void* d_out, int out_size, void* d_ws, size_t ws_size,
                              hipStream_t stream){
  (void)in_sizes; (void)n_in; (void)out_size; (void)d_ws; (void)ws_size;
  const void* data_x = d_in[0];
  const int* ei = (const int*)d_in[1];
  const int* src = ei;
  const int* tgt = ei + NE;
  const void *W1 = d_in[3], *b1 = d_in[4], *gm1 = d_in[5], *be1 = d_in[6];
  const void *W2 = d_in[7], *b2 = d_in[8], *gm2 = d_in[9], *be2 = d_in[10];
  const void *Wrel = d_in[11], *Wself = d_in[12], *rb = d_in[13];
  const void *c1W = d_in[14], *c1b = d_in[15];
  const void *c2W = d_in[16], *c2b = d_in[17];

  k_detect_zero<<<1 + (NN + 255) / 256, 256, 0, stream>>>((const unsigned short*)data_x);
  k_transpose_all<<<(122880 + 255) / 256, 256, 0, stream>>>(W1, W2, Wself, Wrel, c1W, c2W);

  k_deg<<<(NE + 255) / 256, 256, 0, stream>>>(tgt);
  k_scan1<<<SCAN_B, 256, 0, stream>>>();
  k_scan2<<<1, 256, 0, stream>>>();
  k_scan3<<<SCAN_B, 256, 0, stream>>>();
  k_fill<<<(NE + 255) / 256, 256, 0, stream>>>(src, tgt);

  k_gemm12<<<NBLK, 256, 0, stream>>>(data_x, b1, gm1, be1, b2, gm2, be2); // -> bufB
  k_rgcn_f<<<NBLK, 256, 0, stream>>>(rb);                                 // bufB -> bufC
  k_conv_f<<<NBLK, 256, 0, stream>>>(c1b);                                // bufC -> bufA[N,64]
  k_agg_lsm<<<(NN + 31) / 32, 256, 0, stream>>>(c2b, d_out);              // bufA -> out
}